// Round 1
// 134.849 us; speedup vs baseline: 1.2273x; 1.2273x over previous
//
#include <hip/hip_runtime.h>
#include <math.h>

// Problem: out[n,0,i,j] = (1/64) * sum_{c,p,q} w[c]*sqrt(x[n,c,i+p,j+q])*sqrt(z[n,c,p,q])
//   N=16, C=256, k=8, m=63, mo=56.
//
// Shift-GEMM reformulation (the only MFMA-factorable form: filter taps -> M dim):
//   S[n][p*8+q][r*63+s] = sum_c (w[c]*sqrt(z[n,c,p,q])) * sqrt(x[n,c,r,s])
//        -> per-sample GEMM  M=64(pq) x N=3969(pixels) x K=256(channels), bf16 MFMA
//   out[n,i,j] = (1/64) * sum_{p,q} S[n][pq][(i+p)*63 + (j+q)]
//        -> every S element contributes to exactly ONE output: pure gather, no atomics.
//
// Workspace: S = 16*64*3969 fp32 = 16,257,024 bytes in d_ws.

#define NS 16
#define NC 256
#define PQ 64
#define MI 63
#define MO 56
#define NPIX (MI*MI)            // 3969
#define NOUT (MO*MO)            // 3136
#define ZPAD 264                // zs row stride (bf16 elems): 256+8 breaks bank alignment
#define NGROUP ((NPIX + 15)/16) // 249 pixel groups of 16

typedef __attribute__((ext_vector_type(8))) short bf16x8;
typedef __attribute__((ext_vector_type(4))) float f32x4;

static __device__ __forceinline__ short f2bf(float f) {
    // round-to-nearest-even fp32 -> bf16 (inputs are finite, nonnegative)
    union { float f; unsigned u; } v; v.f = f;
    return (short)((v.u + 0x7fffu + ((v.u >> 16) & 1u)) >> 16);
}

// ---------------- Kernel 1: S[pq, pixel] = Zb[pq, c] @ Xb[c, pixel] ----------------
// Grid: (16 samples, 63 group-quads), 256 threads = 4 waves.
// Wave w handles pixel group g = blockIdx.y*4 + w (16 consecutive pixels of sample n),
// computing all 64 pq rows: 4 M-tiles x 8 k-steps of mfma_f32_16x16x32_bf16.
__global__ __launch_bounds__(256, 4)
void sgemm_kernel(const float* __restrict__ z, const float* __restrict__ x,
                  const float* __restrict__ w, float* __restrict__ S) {
    __shared__ short zs[PQ * ZPAD];     // A matrix, bf16: zs[pq][c], 33.8 KB

    const int n   = blockIdx.x;
    const int tid = threadIdx.x;

    // Stage A = w[c]*sqrt(z[n]) once per block. idx = c*64 + pq: coalesced z reads,
    // wave-uniform w[c]; scattered 2B LDS writes (one-time, ~8-way, negligible).
    {
        const float* zb = z + (size_t)n * NC * PQ;
        #pragma unroll 4
        for (int it = 0; it < (NC * PQ) / 256; ++it) {
            int idx = it * 256 + tid;
            int c = idx >> 6, pq = idx & 63;
            zs[pq * ZPAD + c] = f2bf(w[c] * sqrtf(zb[c * PQ + pq]));
        }
    }
    __syncthreads();

    const int wave = tid >> 6, lane = tid & 63;
    const int lm = lane & 15, lg = lane >> 4;
    const int g = blockIdx.y * 4 + wave;
    if (g >= NGROUP) return;            // no barriers after this point

    const int pixbase = g * 16;
    int pix = pixbase + lm;
    if (pix > NPIX - 1) pix = NPIX - 1;  // clamp loads in the 1-pixel tail group

    const float* xb = x + (size_t)n * NC * NPIX + pix;

    f32x4 acc[4];
    #pragma unroll
    for (int mt = 0; mt < 4; ++mt) acc[mt] = (f32x4){0.f, 0.f, 0.f, 0.f};

    #pragma unroll
    for (int kk = 0; kk < 8; ++kk) {
        const int cb = kk * 32 + lg * 8;     // this lane-group's 8 channels
        bf16x8 bfrag;
        #pragma unroll
        for (int j = 0; j < 8; ++j)
            bfrag[j] = f2bf(sqrtf(xb[(size_t)(cb + j) * NPIX]));

        // A-frags from LDS: lane reads pq row (mt*16+lm), channels cb..cb+7 -> ds_read_b128
        #pragma unroll
        for (int mt = 0; mt < 4; ++mt) {
            const bf16x8 afrag = *(const bf16x8*)(&zs[(mt * 16 + lm) * ZPAD + cb]);
            acc[mt] = __builtin_amdgcn_mfma_f32_16x16x32_bf16(afrag, bfrag, acc[mt], 0, 0, 0);
        }
    }

    // D layout (m89, HW-verified): col = lane&15 = pixel, row = (lane>>4)*4 + reg = pq within tile.
    if (pixbase + lm < NPIX) {
        float* Sb = S + (size_t)n * PQ * NPIX + pixbase + lm;
        #pragma unroll
        for (int mt = 0; mt < 4; ++mt)
            #pragma unroll
            for (int t = 0; t < 4; ++t)
                Sb[(size_t)(mt * 16 + lg * 4 + t) * NPIX] = acc[mt][t];
    }
}

// ---------------- Kernel 2: out[n,i,j] = (1/64) sum_pq S[n][pq][(i+p)*63 + j+q] ----------------
// One thread per output; loads are coalesced (consecutive j -> consecutive addresses per (p,q)),
// and overlapping q-windows hit L1. Every output is fully written -> no memset needed.
__global__ __launch_bounds__(256)
void reduce_kernel(const float* __restrict__ S, float* __restrict__ out) {
    const int id = blockIdx.x * 256 + threadIdx.x;
    if (id >= NS * NOUT) return;
    const int n = id / NOUT;
    const int r = id - n * NOUT;
    const int i = r / MO;
    const int j = r - i * MO;

    const float* Sb = S + (size_t)n * PQ * NPIX + i * MI + j;
    float sum = 0.f;
    #pragma unroll
    for (int p = 0; p < 8; ++p) {
        const float* Sp = Sb + (size_t)p * 8 * NPIX + p * MI;
        #pragma unroll
        for (int q = 0; q < 8; ++q)
            sum += Sp[(size_t)q * NPIX + q];
    }
    out[id] = sum * (1.0f / 64.0f);
}

extern "C" void kernel_launch(void* const* d_in, const int* in_sizes, int n_in,
                              void* d_out, int out_size, void* d_ws, size_t ws_size,
                              hipStream_t stream) {
    const float* z = (const float*)d_in[0];   // (16,256,8,8)
    const float* x = (const float*)d_in[1];   // (16,256,63,63)
    const float* w = (const float*)d_in[2];   // (1,256,1,1,1) -> 256 floats
    float* out = (float*)d_out;               // (16,1,56,56)
    float* S = (float*)d_ws;                  // 16.26 MB fp32 scratch

    dim3 g1(NS, (NGROUP + 3) / 4);            // (16, 63) = 1008 blocks
    sgemm_kernel<<<g1, 256, 0, stream>>>(z, x, w, S);

    const int nb = (NS * NOUT + 255) / 256;   // 196 blocks
    reduce_kernel<<<nb, 256, 0, stream>>>(S, out);
}